// Round 9
// baseline (263.143 us; speedup 1.0000x reference)
//
#include <hip/hip_runtime.h>
#include <math.h>

#define L 4096
#define B 8
#define D 1024
#define NH 16
#define COUT 128              // output rows per block (windback amort 2.0x —
                              // accepted to keep 256 blocks at DBLK=1024)
#define WB 128                // windback length (q^128 <= 2.4e-6 worst-case)
#define NCHUNK (L / COUT)     // 32
#define BD 8192               // B*D floats between consecutive l
#define DBLK 1024             // d-values per block = FULL D-row of one batch:
                              // every l-row access is a 4KB contiguous burst
#define TL 4                  // l-rows per LDS tile (16KB)
#define NBUF 4                // quad-buffered (64KB LDS), depth-3 prefetch

#define REP8(F) F(0) F(1) F(2) F(3) F(4) F(5) F(6) F(7)

typedef float f2 __attribute__((ext_vector_type(2)));

__device__ __forceinline__ float sigmoidf(float v) {
    return 1.0f / (1.0f + __expf(-v));
}

// ---- 16 heads per thread as 8 packed-f32 chains (v_pk_fma_f32) ----
#define UPD(i) s##i = __builtin_elementwise_fma(q##i, s##i, xv2);
#define UPDALL UPD(0) UPD(1) UPD(2) UPD(3) UPD(4) UPD(5) UPD(6) UPD(7)
// two y-accumulators to halve the dependent-chain depth
#define ACCA(i) s##i = __builtin_elementwise_fma(q##i, s##i, xv2); \
                yA = __builtin_elementwise_fma(P##i, s##i, yA);
#define ACCB(i) s##i = __builtin_elementwise_fma(q##i, s##i, xv2); \
                yB = __builtin_elementwise_fma(P##i, s##i, yB);
#define ACCALL ACCA(0) ACCB(1) ACCA(2) ACCB(3) ACCA(4) ACCB(5) ACCA(6) ACCB(7)

// async global->LDS, 16B/lane: one instr = 64 lanes x 16B = 1KB contiguous.
#define GLD16(g, l) __builtin_amdgcn_global_load_lds( \
    (const __attribute__((address_space(1))) unsigned int*)(g), \
    (__attribute__((address_space(3))) unsigned int*)(l), 16, 0, 0)

#define VM(n) asm volatile("s_waitcnt vmcnt(" #n ")" ::: "memory")
#define MEMFENCE asm volatile("" ::: "memory")

// ---------------------------------------------------------------------------
// Round 9: segment width to its maximum — DBLK 512 -> 1024. R8 confirmed the
// spatial theory (512B->2KB segments: 2.26->2.72 TB/s, 103->85us, with
// occupancy DOWN — waves never were the limit). The 6.3 TB/s D2D copy
// reference issues ~4KB-contiguous per block per access at huge strides;
// this version matches that shape: a block owns the full D-row of one batch
// (4KB contiguous per l-row), and the 8 b-blocks of a c-group collectively
// sweep fully contiguous 32KB l-rows of x.
//   1024 thr (16 waves), 16 heads/thread. Tile = 4 rows x 4KB; wave wv
//   stages 1KB: row wv>>2, quarter wv&3 (exactly 1 GLD16/wave/tile).
//   NBUF=4 = 64KB static LDS (compiled fine at 64KB in R8). COUT=128 keeps
//   grid at 32x8 = 256 blocks = 1/CU; windback 2.0x accepted (VALUBusy 28%
//   had headroom).
//   vmcnt ladder (per wave: 1 load + 4 stores per output tile; N = VMEM ops
//   issued after the awaited GLD):
//     windback:        VM(2)
//     output r=0/1/2:  VM(2)/VM(6)/VM(10)
//     output r=3..29:  VM(14)   (GLD issued while r<=28)
//     output r=30/31:  VM(13)/VM(12)
// ---------------------------------------------------------------------------
__global__ void __launch_bounds__(1024, 1)
ema_fused(const float* __restrict__ x,
          const float* __restrict__ damp,
          const float* __restrict__ decay,
          const float* __restrict__ ema,
          const float* __restrict__ proj,
          const float* __restrict__ rw,
          float* __restrict__ out) {
    const int tid  = threadIdx.x;         // 0..1023 = d (full row)
    const int lane = tid & 63;
    const int wv   = tid >> 6;            // wave in block: 0..15
    const int c    = blockIdx.x;          // 0..NCHUNK-1
    const int b    = blockIdx.y;          // 0..7
    const int d    = tid;

    __shared__ float lds[NBUF][TL][DBLK];   // 4 x 16KB = 64KB

    const float* dp = damp  + d * NH;
    const float* dc = decay + d * NH;
    const float* de = ema   + d * NH;
    const float* pj = proj  + d * NH;

    // ---- per-head state (8 packed pairs = 16 heads) + projection ----
#define DECLQS(i) f2 q##i, s##i;
    REP8(DECLQS)
#define INITQS(i) { \
        q##i.x = 1.0f - sigmoidf(dp[2*(i)])   * sigmoidf(dc[2*(i)]); \
        q##i.y = 1.0f - sigmoidf(dp[2*(i)+1]) * sigmoidf(dc[2*(i)+1]); \
        s##i.x = 0.0f; s##i.y = 0.0f; }
    REP8(INITQS)
#define DECLP(i) f2 P##i;
    REP8(DECLP)
#define INITP(i) { \
        P##i.x = sigmoidf(dp[2*(i)])   * de[2*(i)]   * pj[2*(i)]   * 0.25f; \
        P##i.y = sigmoidf(dp[2*(i)+1]) * de[2*(i)+1] * pj[2*(i)+1] * 0.25f; }
    REP8(INITP)
    const float w = rw[d];

    // drain parameter loads so the GLD queue accounting below is exact
    VM(0); MEMFENCE;

    const int wb = (c > 0) ? WB : 0;
    const int wt = wb / TL;               // 32 or 0 windback tiles
    const int nt = wt + COUT / TL;        // 64 or 32 tiles total

    // block x base (windback start). Wave wv stages 1KB of each tile:
    // row = wv>>2 of the 4-row tile, quarter = wv&3 of the 4KB row.
    const float* xb = x + (size_t)(c * COUT - wb) * BD + (size_t)b * D;
    const int    srow = wv >> 2;          // 0..3
    const int    sseg = (wv & 3) << 8;    // 0/256/512/768 floats

#define GLD(t) { \
        const float* g_ = xb + (size_t)((t) * TL + srow) * BD + sseg + (lane << 2); \
        float* l_ = &lds[(t) & 3][srow][sseg]; \
        GLD16(g_, l_); }

    // ---- prologue: 3 tiles in flight ----
    GLD(0) GLD(1) GLD(2)
    MEMFENCE;

    // ---- windback: state update only (no stores -> VM(2) exact) ----
    if (c > 0) {
        for (int t = 0; t < WB / TL; ++t) {
            VM(2);
            __builtin_amdgcn_s_barrier();
            MEMFENCE;
            GLD(t + 3)
            MEMFENCE;
            const float* bp = &lds[t & 3][0][tid];
#pragma unroll
            for (int sl = 0; sl < TL; ++sl) {
                float xv = bp[sl * DBLK];
                f2 xv2; xv2.x = xv; xv2.y = xv;
                UPDALL
            }
        }
    }

    // ---- output phase: 32 tiles ----
    float* opb = out + (size_t)(c * COUT) * BD + (size_t)b * D + tid;

#define OTILE(r, KWAIT, DOGLD) { \
        KWAIT; \
        __builtin_amdgcn_s_barrier(); \
        MEMFENCE; \
        if (DOGLD) GLD(wt + (r) + 3) \
        MEMFENCE; \
        const float* bp = &lds[(wt + (r)) & 3][0][tid]; \
        float* op = opb + (size_t)(r) * (TL * BD); \
        _Pragma("unroll") \
        for (int sl = 0; sl < TL; ++sl) { \
            float xv = bp[sl * DBLK]; \
            f2 xv2; xv2.x = xv; xv2.y = xv; \
            f2 yA;  yA.x = xv * w; yA.y = 0.0f; \
            f2 yB;  yB.x = 0.0f;  yB.y = 0.0f; \
            ACCALL \
            f2 yt = yA + yB; \
            float y = yt.x + yt.y; \
            op[(size_t)sl * BD] = fmaxf(y, 0.0f); \
        } }

    OTILE(0, VM(2),  1)
    OTILE(1, VM(6),  1)
    OTILE(2, VM(10), 1)
#pragma unroll
    for (int r = 3; r <= 28; ++r) { OTILE(r, VM(14), 1) }
    OTILE(29, VM(14), 0)
    OTILE(30, VM(13), 0)
    OTILE(31, VM(12), 0)
}

// ---------------------------------------------------------------------------
extern "C" void kernel_launch(void* const* d_in, const int* in_sizes, int n_in,
                              void* d_out, int out_size, void* d_ws, size_t ws_size,
                              hipStream_t stream) {
    const float* x     = (const float*)d_in[0];
    const float* damp  = (const float*)d_in[1];
    const float* decay = (const float*)d_in[2];
    const float* ema   = (const float*)d_in[3];
    const float* proj  = (const float*)d_in[4];
    const float* rw    = (const float*)d_in[5];
    float* out = (float*)d_out;

    // 32 x 8 = 256 blocks x 16 waves = 1 block/CU (64KB LDS each)
    dim3 grid(NCHUNK, B);
    ema_fused<<<grid, 1024, 0, stream>>>(x, damp, decay, ema, proj, rw, out);
}